// Round 5
// baseline (218.793 us; speedup 1.0000x reference)
//
#include <hip/hip_runtime.h>

// Problem constants
#define B_ 256
#define T_ 64
#define N_ 128
#define H_ 128
#define G3 384   // 3*H (gate rows)
#define K2 256   // 2*H (packed matvec K range: [agg ; prev])

// Workspace layout (float offsets)
#define WS_G    0                    // G table: 384*384  (b_ih + W_ih[:, :H] @ emb[e])
#define WS_PW   (WS_G + G3*G3)       // packed transposed weights: 256*384
#define WS_NZC  (WS_PW + K2*G3)      // 128 ints: nonzero counts
#define WS_NZP  (WS_NZC + 128)       // 128*128 int2 pairs (n, w bits)

// ---------------------------------------------------------------------------
// Single prep kernel, 768 blocks x 384 threads, role by blockIdx:
//   [0,384):   G[e][j] = b_ih[j] + sum_k W_ih[j][k] * emb[e][k]
//   [384,512): nz list for adj row (bid-384)
//   [512,768): PW[k][j] = k<128 ? W_ih[j][128+k] : W_hh[j][k-128]
// ---------------------------------------------------------------------------
__global__ void __launch_bounds__(384) prep(
        const float* __restrict__ W_ih, const float* __restrict__ W_hh,
        const float* __restrict__ emb,  const float* __restrict__ b_ih,
        const float* __restrict__ adj,  float* __restrict__ ws) {
    const int bid = blockIdx.x;
    if (bid < 384) {
        __shared__ float es[H_];
        const int e = bid, j = threadIdx.x;
        if (j < H_) es[j] = emb[e * H_ + j];
        __syncthreads();
        float acc = b_ih[j];
        const float4* wrow = (const float4*)(W_ih + j * K2);  // row j, cols [0,128)
        #pragma unroll 8
        for (int i = 0; i < 32; ++i) {
            float4 w = wrow[i];
            acc += w.x * es[4*i];
            acc += w.y * es[4*i + 1];
            acc += w.z * es[4*i + 2];
            acc += w.w * es[4*i + 3];
        }
        (ws + WS_G)[e * G3 + j] = acc;
    } else if (bid < 512) {
        __shared__ float row[N_];
        const int r = bid - 384;
        if (threadIdx.x < N_) row[threadIdx.x] = adj[r * N_ + threadIdx.x];
        __syncthreads();
        if (threadIdx.x == 0) {
            int*  nzc = (int*)(ws + WS_NZC);
            int2* nzp = (int2*)(ws + WS_NZP);
            int cnt = 0;
            for (int n = 0; n < N_; ++n) {
                float w = row[n];
                if (w != 0.0f) { nzp[r * N_ + cnt] = make_int2(n, __float_as_int(w)); ++cnt; }
            }
            int cnt4 = (cnt + 3) & ~3;
            for (int i = cnt; i < cnt4; ++i) nzp[r * N_ + i] = make_int2(0, 0); // w=0 pad
            nzc[r] = cnt;
        }
    } else {
        const int k = bid - 512, j = threadIdx.x;
        (ws + WS_PW)[k * G3 + j] = (k < H_) ? W_ih[j * K2 + H_ + k]
                                            : W_hh[j * H_ + (k - H_)];
    }
}

// ---------------------------------------------------------------------------
// Main kernel: one block per batch element. 512 threads = 8 waves (2/SIMD ->
// 256-VGPR cap). Thread (kc = tid>>5 in [0,16), g = tid&31) owns K-chunk
// [16kc,16kc+16) x rows {g, g+32, ..., g+352}: 192 weights, ASM-PINNED into
// VGPRs (compiler cannot rematerialize from memory; 192+~45 < 256 cap).
// Per step, 3 phases:
//  A : matvec partials pl[kc][row] (4 b128 vector reads/thread); threads 0-63
//      also finalize prev step's logit; gate threads prefetch prevreg+G row.
//  B1: threads 0-383 reduce 16 partials -> gsA (agg half, kc 0-7) and gsB
//      (hidden half, kc 8-15); threads 384-511 store prev logits row + stage
//      next nz row.
//  B2: threads 0-127 gates+h-write+red; 128-255 dup gates + agg(s+1) with
//      hnew substitution (bit-exact, avoids extra barrier).
// ---------------------------------------------------------------------------
__global__ void __launch_bounds__(512, 2) gkt_main(
        const int* __restrict__ task_seq, const int* __restrict__ status_seq,
        const float* __restrict__ b_hh,   const float* __restrict__ w_pred,
        const float* __restrict__ b_pred, const float* __restrict__ ws,
        float* __restrict__ out) {
    __shared__ __align__(16) float h_lds[N_ * H_];   // 64 KB state
    __shared__ __align__(16) float aggbuf[H_];       // agg vector for current step
    __shared__ float pl[16 * G3];                    // partials [kc][row], 24 KB
    __shared__ float gsA[G3], gsB[G3];               // reduced partials (agg / hidden)
    __shared__ float red[H_];                        // logit-dot partials
    __shared__ float Ll[N_];                         // running logits
    __shared__ int2  nzbuf[N_];                      // staged nz list (next task)
    __shared__ int   nz_cnt;
    __shared__ int   tasks_l[T_], stats_l[T_];

    const int b   = blockIdx.x;
    const int tid = threadIdx.x;
    const int kc  = tid >> 5;            // K-chunk [0,16), wave-uniform pairs
    const int g   = tid & 31;            // row-group

    const float* G   = ws + WS_G;
    const float* PW  = ws + WS_PW;
    const int*   nzc = (const int*)(ws + WS_NZC);
    const int2*  nzp = (const int2*)(ws + WS_NZP);

    // ---- prologue: 192 weights, loaded then PINNED (opaque to rematerializer)
    float w[192];
    #pragma unroll
    for (int r = 0; r < 12; ++r) {
        #pragma unroll
        for (int kk = 0; kk < 16; ++kk)
            w[r * 16 + kk] = PW[(kc * 16 + kk) * G3 + (g + r * 32)];
    }
    #pragma unroll
    for (int i = 0; i < 192; ++i) asm volatile("" : "+v"(w[i]));

    const float bp = b_pred[0];
    const int tg = tid & 127;
    float bhr = 0.f, bhz = 0.f, bhn = 0.f, wpt = 0.f;
    if (tid < 256) { bhr = b_hh[tg]; bhz = b_hh[128 + tg]; bhn = b_hh[256 + tg]; }
    if (tid < 128) wpt = w_pred[tg];

    // ---- init
    for (int i = tid; i < N_ * H_; i += 512) h_lds[i] = 0.0f;
    if (tid < T_)          tasks_l[tid]      = task_seq[b * T_ + tid];
    else if (tid < 2*T_)   stats_l[tid - T_] = status_seq[b * T_ + (tid - T_)];
    if (tid >= 128 && tid < 256) { Ll[tid-128] = bp; aggbuf[tid-128] = 0.0f; }
    __syncthreads();

    #pragma unroll 1
    for (int s = 0; s < T_; ++s) {
        const int task = tasks_l[s];

        // ---- Phase A ----------------------------------------------------
        float prevreg = 0.f, g0 = 0.f, g1 = 0.f, g2 = 0.f;
        if (tid < 256) {                              // prefetch for B2
            prevreg = h_lds[task * H_ + tg];
            const int e = task * 3 + stats_l[s];
            g0 = G[e * G3 + tg];
            g1 = G[e * G3 + 128 + tg];
            g2 = G[e * G3 + 256 + tg];
        }
        {
            const float* vbase = (kc < 8) ? (aggbuf + kc * 16)
                                          : (h_lds + task * H_ + (kc - 8) * 16);
            const float4* vb4 = (const float4*)vbase;
            const float4 v0 = vb4[0], v1 = vb4[1], v2 = vb4[2], v3 = vb4[3];
            const float vv[16] = {v0.x, v0.y, v0.z, v0.w, v1.x, v1.y, v1.z, v1.w,
                                  v2.x, v2.y, v2.z, v2.w, v3.x, v3.y, v3.z, v3.w};
            #pragma unroll
            for (int r = 0; r < 12; ++r) {
                float acc = 0.f;
                #pragma unroll
                for (int kk = 0; kk < 16; ++kk) acc += w[r * 16 + kk] * vv[kk];
                pl[kc * G3 + g + r * 32] = acc;
            }
        }
        if (tid < 64 && s > 0) {                      // finalize logit of step s-1
            float x = red[tid] + red[tid + 64];
            #pragma unroll
            for (int off = 32; off > 0; off >>= 1) x += __shfl_xor(x, off, 64);
            if (tid == 0) Ll[tasks_l[s - 1]] = x + bp;
        }
        __syncthreads();

        // ---- Phase B1 ---------------------------------------------------
        if (tid < G3) {
            float sA = pl[tid];
            #pragma unroll
            for (int k2 = 1; k2 < 8; ++k2)  sA += pl[k2 * G3 + tid];
            float sB = pl[8 * G3 + tid];
            #pragma unroll
            for (int k2 = 9; k2 < 16; ++k2) sB += pl[k2 * G3 + tid];
            gsA[tid] = sA;
            gsB[tid] = sB;
        } else {
            const int t = tid - G3;                   // [0,128)
            if (s > 0) out[(size_t)b * T_ * N_ + (size_t)(s - 1) * N_ + t] = Ll[t];
            if (s + 1 < T_) {                         // stage next step's nz row
                const int tn = tasks_l[s + 1];
                nzbuf[t] = nzp[tn * N_ + t];
                if (t == 0) nz_cnt = nzc[tn];
            }
        }
        __syncthreads();

        // ---- Phase B2 ---------------------------------------------------
        if (tid < 256) {
            float sr  = g0 + bhr + gsA[tg] + gsB[tg];
            float sz  = g1 + bhz + gsA[128 + tg] + gsB[128 + tg];
            float in_ = g2 + gsA[256 + tg];           // i_n (agg/x half)
            float hn_ = bhn + gsB[256 + tg];          // h_n (hidden half)
            float r = 1.0f / (1.0f + expf(-sr));
            float z = 1.0f / (1.0f + expf(-sz));
            float n = tanhf(in_ + r * hn_);
            float hnew = (1.0f - z) * n + z * prevreg;
            if (tid < 128) {
                h_lds[task * H_ + tg] = hnew;
                red[tg] = hnew * wpt;
            } else if (s + 1 < T_) {                  // agg for step s+1
                float acc = 0.0f;
                const int cnt4 = (nz_cnt + 3) & ~3;
                for (int i = 0; i < cnt4; i += 4) {
                    int2 p0 = nzbuf[i], p1 = nzbuf[i+1], p2 = nzbuf[i+2], p3 = nzbuf[i+3];
                    float h0 = (p0.x == task) ? hnew : h_lds[p0.x * H_ + tg];
                    float h1 = (p1.x == task) ? hnew : h_lds[p1.x * H_ + tg];
                    float h2 = (p2.x == task) ? hnew : h_lds[p2.x * H_ + tg];
                    float h3 = (p3.x == task) ? hnew : h_lds[p3.x * H_ + tg];
                    acc += __int_as_float(p0.y) * h0;
                    acc += __int_as_float(p1.y) * h1;
                    acc += __int_as_float(p2.y) * h2;
                    acc += __int_as_float(p3.y) * h3;
                }
                aggbuf[tg] = acc;
            }
        }
        __syncthreads();
    }

    // ---- epilogue: final logit update, last logits row, final hidden state
    if (tid < 64) {
        float x = red[tid] + red[tid + 64];
        #pragma unroll
        for (int off = 32; off > 0; off >>= 1) x += __shfl_xor(x, off, 64);
        if (tid == 0) Ll[tasks_l[T_ - 1]] = x + bp;
    }
    __syncthreads();
    if (tid < N_) out[(size_t)b * T_ * N_ + (size_t)(T_ - 1) * N_ + tid] = Ll[tid];
    {
        float4* dst = (float4*)(out + (size_t)B_ * T_ * N_ + (size_t)b * N_ * H_);
        const float4* src = (const float4*)h_lds;
        for (int i = tid; i < N_ * H_ / 4; i += 512) dst[i] = src[i];
    }
}

// ---------------------------------------------------------------------------
extern "C" void kernel_launch(void* const* d_in, const int* in_sizes, int n_in,
                              void* d_out, int out_size, void* d_ws, size_t ws_size,
                              hipStream_t stream) {
    const int*   task = (const int*)d_in[0];
    const int*   stat = (const int*)d_in[1];
    const float* adj  = (const float*)d_in[2];
    const float* emb  = (const float*)d_in[3];
    const float* Wih  = (const float*)d_in[4];
    const float* Whh  = (const float*)d_in[5];
    const float* bih  = (const float*)d_in[6];
    const float* bhh  = (const float*)d_in[7];
    const float* wp   = (const float*)d_in[8];
    const float* bp   = (const float*)d_in[9];
    float* out = (float*)d_out;
    float* ws  = (float*)d_ws;

    prep    <<<768, 384, 0, stream>>>(Wih, Whh, emb, bih, adj, ws);
    gkt_main<<<256, 512, 0, stream>>>(task, stat, bhh, wp, bp, ws, out);
}

// Round 6
// 218.241 us; speedup vs baseline: 1.0025x; 1.0025x over previous
//
#include <hip/hip_runtime.h>

// Problem constants
#define B_ 256
#define T_ 64
#define N_ 128
#define H_ 128
#define G3 384   // 3*H (gate rows)
#define K2 256   // 2*H (packed matvec K range: [agg ; prev])

// Workspace layout (float offsets)
#define WS_G    0                    // G table: 384*384  (b_ih + W_ih[:, :H] @ emb[e])
#define WS_PW   (WS_G + G3*G3)       // packed transposed weights: 256*384
#define WS_NZC  (WS_PW + K2*G3)      // 128 ints: nonzero counts
#define WS_NZP  (WS_NZC + 128)       // 128*128 int2 pairs (n, w bits)

// ---------------------------------------------------------------------------
// Single prep kernel (unchanged from round 5)
// ---------------------------------------------------------------------------
__global__ void __launch_bounds__(384) prep(
        const float* __restrict__ W_ih, const float* __restrict__ W_hh,
        const float* __restrict__ emb,  const float* __restrict__ b_ih,
        const float* __restrict__ adj,  float* __restrict__ ws) {
    const int bid = blockIdx.x;
    if (bid < 384) {
        __shared__ float es[H_];
        const int e = bid, j = threadIdx.x;
        if (j < H_) es[j] = emb[e * H_ + j];
        __syncthreads();
        float acc = b_ih[j];
        const float4* wrow = (const float4*)(W_ih + j * K2);  // row j, cols [0,128)
        #pragma unroll 8
        for (int i = 0; i < 32; ++i) {
            float4 w = wrow[i];
            acc += w.x * es[4*i];
            acc += w.y * es[4*i + 1];
            acc += w.z * es[4*i + 2];
            acc += w.w * es[4*i + 3];
        }
        (ws + WS_G)[e * G3 + j] = acc;
    } else if (bid < 512) {
        __shared__ float row[N_];
        const int r = bid - 384;
        if (threadIdx.x < N_) row[threadIdx.x] = adj[r * N_ + threadIdx.x];
        __syncthreads();
        if (threadIdx.x == 0) {
            int*  nzc = (int*)(ws + WS_NZC);
            int2* nzp = (int2*)(ws + WS_NZP);
            int cnt = 0;
            for (int n = 0; n < N_; ++n) {
                float w = row[n];
                if (w != 0.0f) { nzp[r * N_ + cnt] = make_int2(n, __float_as_int(w)); ++cnt; }
            }
            int cnt4 = (cnt + 3) & ~3;
            for (int i = cnt; i < cnt4; ++i) nzp[r * N_ + i] = make_int2(0, 0); // w=0 pad
            nzc[r] = cnt;
        }
    } else {
        const int k = bid - 512, j = threadIdx.x;
        (ws + WS_PW)[k * G3 + j] = (k < H_) ? W_ih[j * K2 + H_ + k]
                                            : W_hh[j * H_ + (k - H_)];
    }
}

// ---- macro machinery: 192 NAMED scalar weights (no arrays -> no rule-#20
// scratch demotion). Thread (kc=tid>>5, g=tid&31) owns K-chunk [16kc,16kc+16)
// x rows {g+32r : r=0..11}. w<r>_<k> = PW[(kc*16+k)*G3 + g + r*32].
#define FOR16(M, r) M(r,0) M(r,1) M(r,2) M(r,3) M(r,4) M(r,5) M(r,6) M(r,7) \
                    M(r,8) M(r,9) M(r,10) M(r,11) M(r,12) M(r,13) M(r,14) M(r,15)
#define FOR12(M) M(0) M(1) M(2) M(3) M(4) M(5) M(6) M(7) M(8) M(9) M(10) M(11)

#define DECLW(r,k)  float w##r##_##k;
#define LOADW(r,k)  w##r##_##k = PWt[(k) * G3 + (r) * 32];
#define PINW(r,k)   asm volatile("" : "+v"(w##r##_##k));
#define FMA0(r,k)   acc##r += w##r##_##k * vv##k;

#define ROW_DECL(r)  DECLW(r,0) DECLW(r,1) DECLW(r,2) DECLW(r,3) DECLW(r,4) DECLW(r,5) DECLW(r,6) DECLW(r,7) DECLW(r,8) DECLW(r,9) DECLW(r,10) DECLW(r,11) DECLW(r,12) DECLW(r,13) DECLW(r,14) DECLW(r,15)
#define ROW_LOAD(r)  FOR16(LOADW, r)
#define ROW_PIN(r)   FOR16(PINW, r)
#define ROW_FMA(r)   float acc##r = 0.f; FOR16(FMA0, r)
#define ROW_STORE(r) pl[kc * G3 + g + (r) * 32] = acc##r;

// ---------------------------------------------------------------------------
// Main kernel: one block per batch element. 512 threads = 8 waves (2/SIMD ->
// 256-VGPR budget; LDS 96KB forces 1 block/CU so no occupancy incentive to
// spill). 192 named-scalar weights pinned in VGPRs; peak need ~240 < 256.
// Step structure identical to round 5 (3 phases, bit-exact math).
// ---------------------------------------------------------------------------
__global__ void __launch_bounds__(512, 2) gkt_main(
        const int* __restrict__ task_seq, const int* __restrict__ status_seq,
        const float* __restrict__ b_hh,   const float* __restrict__ w_pred,
        const float* __restrict__ b_pred, const float* __restrict__ ws,
        float* __restrict__ out) {
    __shared__ __align__(16) float h_lds[N_ * H_];   // 64 KB state
    __shared__ __align__(16) float aggbuf[H_];       // agg vector for current step
    __shared__ float pl[16 * G3];                    // partials [kc][row], 24 KB
    __shared__ float gsA[G3], gsB[G3];               // reduced partials (agg / hidden)
    __shared__ float red[H_];                        // logit-dot partials
    __shared__ float Ll[N_];                         // running logits
    __shared__ int2  nzbuf[N_];                      // staged nz list (next task)
    __shared__ int   nz_cnt;
    __shared__ int   tasks_l[T_], stats_l[T_];

    const int b   = blockIdx.x;
    const int tid = threadIdx.x;
    const int kc  = tid >> 5;            // K-chunk [0,16)
    const int g   = tid & 31;            // row-group

    const float* G   = ws + WS_G;
    const float* PW  = ws + WS_PW;
    const int*   nzc = (const int*)(ws + WS_NZC);
    const int2*  nzp = (const int2*)(ws + WS_NZP);

    // ---- prologue: 192 named scalar weights, loaded then pinned
    FOR12(ROW_DECL)
    {
        const float* PWt = PW + (kc * 16) * G3 + g;
        FOR12(ROW_LOAD)
    }
    FOR12(ROW_PIN)

    const float bp = b_pred[0];
    const int tg = tid & 127;
    float bhr = 0.f, bhz = 0.f, bhn = 0.f, wpt = 0.f;
    if (tid < 256) { bhr = b_hh[tg]; bhz = b_hh[128 + tg]; bhn = b_hh[256 + tg]; }
    if (tid < 128) wpt = w_pred[tg];

    // ---- init
    for (int i = tid; i < N_ * H_; i += 512) h_lds[i] = 0.0f;
    if (tid < T_)          tasks_l[tid]      = task_seq[b * T_ + tid];
    else if (tid < 2*T_)   stats_l[tid - T_] = status_seq[b * T_ + (tid - T_)];
    if (tid >= 128 && tid < 256) { Ll[tid-128] = bp; aggbuf[tid-128] = 0.0f; }
    __syncthreads();

    #pragma unroll 1
    for (int s = 0; s < T_; ++s) {
        FOR12(ROW_PIN)                                // re-assert VGPR residency
        const int task = tasks_l[s];

        // ---- Phase A ----------------------------------------------------
        float prevreg = 0.f, g0 = 0.f, g1 = 0.f, g2 = 0.f;
        if (tid < 256) {                              // prefetch for B2
            prevreg = h_lds[task * H_ + tg];
            const int e = task * 3 + stats_l[s];
            g0 = G[e * G3 + tg];
            g1 = G[e * G3 + 128 + tg];
            g2 = G[e * G3 + 256 + tg];
        }
        {
            const float* vbase = (kc < 8) ? (aggbuf + kc * 16)
                                          : (h_lds + task * H_ + (kc - 8) * 16);
            const float4* vb4 = (const float4*)vbase;
            const float4 va = vb4[0], vb = vb4[1], vc = vb4[2], vd = vb4[3];
            const float vv0 = va.x, vv1 = va.y, vv2  = va.z, vv3  = va.w;
            const float vv4 = vb.x, vv5 = vb.y, vv6  = vb.z, vv7  = vb.w;
            const float vv8 = vc.x, vv9 = vc.y, vv10 = vc.z, vv11 = vc.w;
            const float vv12 = vd.x, vv13 = vd.y, vv14 = vd.z, vv15 = vd.w;
            FOR12(ROW_FMA)
            FOR12(ROW_STORE)
        }
        if (tid < 64 && s > 0) {                      // finalize logit of step s-1
            float x = red[tid] + red[tid + 64];
            #pragma unroll
            for (int off = 32; off > 0; off >>= 1) x += __shfl_xor(x, off, 64);
            if (tid == 0) Ll[tasks_l[s - 1]] = x + bp;
        }
        __syncthreads();

        // ---- Phase B1 ---------------------------------------------------
        if (tid < G3) {
            float sA = pl[tid];
            #pragma unroll
            for (int k2 = 1; k2 < 8; ++k2)  sA += pl[k2 * G3 + tid];
            float sB = pl[8 * G3 + tid];
            #pragma unroll
            for (int k2 = 9; k2 < 16; ++k2) sB += pl[k2 * G3 + tid];
            gsA[tid] = sA;
            gsB[tid] = sB;
        } else {
            const int t = tid - G3;                   // [0,128)
            if (s > 0) out[(size_t)b * T_ * N_ + (size_t)(s - 1) * N_ + t] = Ll[t];
            if (s + 1 < T_) {                         // stage next step's nz row
                const int tn = tasks_l[s + 1];
                nzbuf[t] = nzp[tn * N_ + t];
                if (t == 0) nz_cnt = nzc[tn];
            }
        }
        __syncthreads();

        // ---- Phase B2 ---------------------------------------------------
        if (tid < 256) {
            float sr  = g0 + bhr + gsA[tg] + gsB[tg];
            float sz  = g1 + bhz + gsA[128 + tg] + gsB[128 + tg];
            float in_ = g2 + gsA[256 + tg];           // i_n (agg/x half)
            float hn_ = bhn + gsB[256 + tg];          // h_n (hidden half)
            float r = 1.0f / (1.0f + expf(-sr));
            float z = 1.0f / (1.0f + expf(-sz));
            float n = tanhf(in_ + r * hn_);
            float hnew = (1.0f - z) * n + z * prevreg;
            if (tid < 128) {
                h_lds[task * H_ + tg] = hnew;
                red[tg] = hnew * wpt;
            } else if (s + 1 < T_) {                  // agg for step s+1
                float acc = 0.0f;
                const int cnt4 = (nz_cnt + 3) & ~3;
                for (int i = 0; i < cnt4; i += 4) {
                    int2 p0 = nzbuf[i], p1 = nzbuf[i+1], p2 = nzbuf[i+2], p3 = nzbuf[i+3];
                    float h0 = (p0.x == task) ? hnew : h_lds[p0.x * H_ + tg];
                    float h1 = (p1.x == task) ? hnew : h_lds[p1.x * H_ + tg];
                    float h2 = (p2.x == task) ? hnew : h_lds[p2.x * H_ + tg];
                    float h3 = (p3.x == task) ? hnew : h_lds[p3.x * H_ + tg];
                    acc += __int_as_float(p0.y) * h0;
                    acc += __int_as_float(p1.y) * h1;
                    acc += __int_as_float(p2.y) * h2;
                    acc += __int_as_float(p3.y) * h3;
                }
                aggbuf[tg] = acc;
            }
        }
        __syncthreads();
    }

    // ---- epilogue: final logit update, last logits row, final hidden state
    if (tid < 64) {
        float x = red[tid] + red[tid + 64];
        #pragma unroll
        for (int off = 32; off > 0; off >>= 1) x += __shfl_xor(x, off, 64);
        if (tid == 0) Ll[tasks_l[T_ - 1]] = x + bp;
    }
    __syncthreads();
    if (tid < N_) out[(size_t)b * T_ * N_ + (size_t)(T_ - 1) * N_ + tid] = Ll[tid];
    {
        float4* dst = (float4*)(out + (size_t)B_ * T_ * N_ + (size_t)b * N_ * H_);
        const float4* src = (const float4*)h_lds;
        for (int i = tid; i < N_ * H_ / 4; i += 512) dst[i] = src[i];
    }
}

// ---------------------------------------------------------------------------
extern "C" void kernel_launch(void* const* d_in, const int* in_sizes, int n_in,
                              void* d_out, int out_size, void* d_ws, size_t ws_size,
                              hipStream_t stream) {
    const int*   task = (const int*)d_in[0];
    const int*   stat = (const int*)d_in[1];
    const float* adj  = (const float*)d_in[2];
    const float* emb  = (const float*)d_in[3];
    const float* Wih  = (const float*)d_in[4];
    const float* Whh  = (const float*)d_in[5];
    const float* bih  = (const float*)d_in[6];
    const float* bhh  = (const float*)d_in[7];
    const float* wp   = (const float*)d_in[8];
    const float* bp   = (const float*)d_in[9];
    float* out = (float*)d_out;
    float* ws  = (float*)d_ws;

    prep    <<<768, 384, 0, stream>>>(Wih, Whh, emb, bih, adj, ws);
    gkt_main<<<256, 512, 0, stream>>>(task, stat, bhh, wp, bp, ws, out);
}